// Round 9
// baseline (284.743 us; speedup 1.0000x reference)
//
#include <hip/hip_runtime.h>

typedef __bf16  bf16x8 __attribute__((ext_vector_type(8)));
typedef float   f32x16 __attribute__((ext_vector_type(16)));

__device__ __forceinline__ unsigned short f2bf(float f) {
    union { float f; unsigned int u; } v; v.f = f;
    unsigned int r = (v.u + 0x7fffu + ((v.u >> 16) & 1u)) >> 16;
    return (unsigned short)r;
}

__device__ __forceinline__ bf16x8 neg8(bf16x8 v) {
    union { bf16x8 b; unsigned u[4]; } t; t.b = v;
    t.u[0] ^= 0x80008000u; t.u[1] ^= 0x80008000u;
    t.u[2] ^= 0x80008000u; t.u[3] ^= 0x80008000u;
    return t.b;
}

// ---------------------------------------------------------------------------
// Kernel A (verified R2 version, untouched): weight transform U = G g G^T,
// bf16 in MFMA B-fragment order: Up[((ad*16 + cg)*256 + k)*8 + j], c = cg*8+j
// ---------------------------------------------------------------------------
__global__ void wino_wtrans(const float* __restrict__ w, unsigned short* __restrict__ Up) {
    int k = blockIdx.x;        // 0..255
    int c = threadIdx.x;       // 0..127
    const float* g = w + (k * 128 + c) * 9;
    float g00=g[0],g01=g[1],g02=g[2],g10=g[3],g11=g[4],g12=g[5],g20=g[6],g21=g[7],g22=g[8];
    float T[4][3];
    T[0][0]=g00;                    T[0][1]=g01;                    T[0][2]=g02;
    T[1][0]=0.5f*(g00+g10+g20);     T[1][1]=0.5f*(g01+g11+g21);     T[1][2]=0.5f*(g02+g12+g22);
    T[2][0]=0.5f*(g00-g10+g20);     T[2][1]=0.5f*(g01-g11+g21);     T[2][2]=0.5f*(g02-g12+g22);
    T[3][0]=g20;                    T[3][1]=g21;                    T[3][2]=g22;
    int cg = c >> 3, j = c & 7;
    #pragma unroll
    for (int a = 0; a < 4; ++a) {
        float u0 = T[a][0];
        float u1 = 0.5f*(T[a][0]+T[a][1]+T[a][2]);
        float u2 = 0.5f*(T[a][0]-T[a][1]+T[a][2]);
        float u3 = T[a][2];
        float uu[4] = {u0,u1,u2,u3};
        #pragma unroll
        for (int d = 0; d < 4; ++d) {
            Up[(((size_t)((a*4+d)*16 + cg))*256 + k)*8 + j] = f2bf(uu[d]);
        }
    }
}

// ---------------------------------------------------------------------------
// Fused kernel = R5 (verified) with ONE change: x is staged into LDS via
// async global_load_lds (zero registers) instead of per-thread VGPR loads.
// Per 16-c chunk, fully-barriered 2-phase (NO double buffer):
//   [vmcnt(0); barrier]  T: read Xraw(LDS) -> transform -> pack -> write V
//   [barrier]  issue GLOAD(chunk+1) -> Xraw (DMA fills under MFMA)
//              MFMA on V (chain-folded inverse transform, R5-verified)
// Hazards: every LDS region's writer/reader pairs are barrier-separated;
// the DMA is issued after its reader's barrier and drained by vmcnt(0)
// before the next reader's barrier. LDS 32KB Xraw + 32KB V -> 2 blocks/CU.
// ---------------------------------------------------------------------------
__global__ __launch_bounds__(512, 4) void wino_fused(
        const float* __restrict__ x, const unsigned short* __restrict__ Up,
        const float* __restrict__ bias, float* __restrict__ out)
{
    __shared__ float          Xraw[32*256];     // 32 KB: block g = cl*2+sr, 1KB each
    __shared__ unsigned short Vs[16*2*64*8];    // 32 KB: [ad][cgb][n][j] bf16

    const bf16x8* U8 = (const bf16x8*)Up;
    const int t  = threadIdx.x;
    const int by = blockIdx.x;      // 0..1   k-split (fast axis)
    const int bx = blockIdx.y;      // 0..495 row-pair

    // ---- transform-phase thread mapping: t = [cgb][rsel][qh][l4][jp] ----
    const int jp   = t & 3;
    const int l4   = (t >> 2) & 15;
    const int qh   = (t >> 6) & 1;
    const int rsel = (t >> 7) & 1;
    const int cgb  = (t >> 8) & 1;
    const int sq   = qh * 16 + l4;           // 0..31
    const int nloc_s = rsel * 32 + sq;
    const bool valid = (sq < 31);

    // ---- mfma mapping ----
    const int lane = t & 63, wave = t >> 6;
    const int l31 = lane & 31, q2 = lane >> 5;
    const int wn = wave & 1, wk = wave >> 1;        // 2 n-rows x 4 k-tiles
    const int row = bx * 2 + wn;
    const int k0  = by * 128 + wk * 32;
    const int bOff = k0 + l31;                      // + (ad*16 + chunk*2 + q2)*256
    const int aOff = wn * 32 + l31;

    // ---- gload base pointers: this wave stages blocks g = wave*4 + bi ----
    // block g holds x[c = chunk*16 + (g>>1)][srow = bx*2 + (g&1)] rows 2p..2p+3,
    // all 64 cols; lane l writes Xraw[g*256 + (l>>4)*64 + (l&15)*4] (HW: base+l*16B)
    const float* xg[4];
    #pragma unroll
    for (int bi = 0; bi < 4; ++bi) {
        const int sr  = bi & 1;
        const int srg = bx * 2 + sr;
        const int bg = srg / 31, pg = srg % 31;
        xg[bi] = x + (((size_t)bg * 128) * 64 + 2 * pg + (lane >> 4)) * 64 + (lane & 15) * 4;
    }
    const int clb = wave * 2;       // cl = clb + (bi>>1)

    f32x16 Y00, Y01, Y10, Y11;
    #pragma unroll
    for (int z = 0; z < 16; ++z) { Y00[z]=0.f; Y01[z]=0.f; Y10[z]=0.f; Y11[z]=0.f; }

#define GLOAD(CHK) {                                                           \
    _Pragma("unroll")                                                          \
    for (int bi = 0; bi < 4; ++bi) {                                           \
        const int cl_ = clb + (bi >> 1);                                       \
        const float* gp_ = xg[bi] + (size_t)((CHK)*16 + cl_) * 4096;           \
        __builtin_amdgcn_global_load_lds(                                      \
            (const __attribute__((address_space(1))) void*)gp_,                \
            (__attribute__((address_space(3))) void*)&Xraw[(wave*4 + bi)*256], \
            16, 0, 0);                                                         \
    } }

    // prologue: stage chunk 0 (one-time exposed latency)
    GLOAD(0);

    for (int chunk = 0; chunk < 8; ++chunk) {
        asm volatile("s_waitcnt vmcnt(0)" ::: "memory");  // this wave's DMA landed
        __syncthreads();   // all waves' DMA visible; prev MFMA's V-reads done

        // ---------------- T phase: Xraw -> transform -> pack -> V ------------
        {
            unsigned pk[4][4];
            unsigned* dst = (unsigned*)Vs;
            #pragma unroll
            for (int ch = 0; ch < 2; ++ch) {
                const int g2 = (cgb*8 + jp*2 + ch)*2 + rsel;
                const float* xr = &Xraw[g2*256 + 2*sq];
                float dd[4][4];
                #pragma unroll
                for (int i = 0; i < 4; ++i) {
                    if (valid) {
                        float2 u0 = *(const float2*)(xr + i*64);
                        float2 u1 = *(const float2*)(xr + i*64 + 2);
                        dd[i][0]=u0.x; dd[i][1]=u0.y; dd[i][2]=u1.x; dd[i][3]=u1.y;
                    } else {
                        dd[i][0]=0.f; dd[i][1]=0.f; dd[i][2]=0.f; dd[i][3]=0.f;
                    }
                }
                float s[4][4];
                #pragma unroll
                for (int jj = 0; jj < 4; ++jj) {
                    s[0][jj] = dd[0][jj] - dd[2][jj];
                    s[1][jj] = dd[1][jj] + dd[2][jj];
                    s[2][jj] = dd[2][jj] - dd[1][jj];
                    s[3][jj] = dd[1][jj] - dd[3][jj];
                }
                #pragma unroll
                for (int a = 0; a < 4; ++a) {
                    float v0 = s[a][0] - s[a][2];
                    float v1 = s[a][1] + s[a][2];
                    float v2 = s[a][2] - s[a][1];
                    float v3 = s[a][1] - s[a][3];
                    if (ch == 0) {
                        pk[a][0] = f2bf(v0); pk[a][1] = f2bf(v1);
                        pk[a][2] = f2bf(v2); pk[a][3] = f2bf(v3);
                    } else {
                        pk[a][0] |= (unsigned)f2bf(v0) << 16;
                        pk[a][1] |= (unsigned)f2bf(v1) << 16;
                        pk[a][2] |= (unsigned)f2bf(v2) << 16;
                        pk[a][3] |= (unsigned)f2bf(v3) << 16;
                    }
                }
            }
            const int base = cgb*256 + nloc_s*4 + jp;
            #pragma unroll
            for (int a = 0; a < 4; ++a)
                #pragma unroll
                for (int d = 0; d < 4; ++d)
                    dst[(a*4 + d)*512 + base] = pk[a][d];
        }
        __syncthreads();   // V ready; Xraw fully consumed -> DMA may refill

        if (chunk < 7) GLOAD(chunk + 1);   // async DMA fills Xraw under MFMA

        // ---------------- MFMA phase: fold chained into accumulators ---------
        const bf16x8* va = (const bf16x8*)Vs;
        __builtin_amdgcn_s_setprio(1);
        #pragma unroll
        for (int ad = 0; ad < 16; ++ad) {
            const int A_ = ad >> 2, D_ = ad & 3;
            const bool t00 = (A_ <= 2) && (D_ <= 2);
            const bool t01 = (A_ <= 2) && (D_ >= 1);
            const bool t10 = (A_ >= 1) && (D_ <= 2);
            const bool t11 = (A_ >= 1) && (D_ >= 1);
            const bool sd = (D_ >= 2), sa = (A_ >= 2);
            const bool needn = (t01 && sd) || (t10 && sa) || (t11 && (sa != sd));
            bf16x8 av = va[(ad*2 + q2)*64 + aOff];
            bf16x8 bv = U8[(size_t)(ad*16 + chunk*2 + q2)*256 + bOff];
            bf16x8 nv = needn ? neg8(av) : av;
            if (t00) Y00 = __builtin_amdgcn_mfma_f32_32x32x16_bf16(av, bv, Y00, 0, 0, 0);
            if (t01) Y01 = __builtin_amdgcn_mfma_f32_32x32x16_bf16(sd ? nv : av, bv, Y01, 0, 0, 0);
            if (t10) Y10 = __builtin_amdgcn_mfma_f32_32x32x16_bf16(sa ? nv : av, bv, Y10, 0, 0, 0);
            if (t11) Y11 = __builtin_amdgcn_mfma_f32_32x32x16_bf16((sa != sd) ? nv : av, bv, Y11, 0, 0, 0);
        }
        __builtin_amdgcn_s_setprio(0);
    }

    // Epilogue: lane owns k-plane k0+l31; C/D row r -> q = (r&3)+8*(r>>2)+4*q2
    int b = row / 31, p = row % 31;
    int k = k0 + l31;
    float bvs = bias[k];
    float* op = out + (size_t)(b*256 + k) * 62 * 62;
    #pragma unroll
    for (int r = 0; r < 16; ++r) {
        int q = (r & 3) + 8*(r >> 2) + 4*q2;
        if (q < 31) {
            *(float2*)(op + (2*p+0)*62 + 2*q) = make_float2(Y00[r] + bvs, Y01[r] + bvs);
            *(float2*)(op + (2*p+1)*62 + 2*q) = make_float2(Y10[r] + bvs, Y11[r] + bvs);
        }
    }
#undef GLOAD
}

// ---------------------------------------------------------------------------
extern "C" void kernel_launch(void* const* d_in, const int* in_sizes, int n_in,
                              void* d_out, int out_size, void* d_ws, size_t ws_size,
                              hipStream_t stream) {
    const float* x    = (const float*)d_in[0];
    const float* w    = (const float*)d_in[1];
    const float* bias = (const float*)d_in[2];
    float* out = (float*)d_out;

    unsigned short* Up = (unsigned short*)d_ws;   // 16*16*256*8 bf16 = 1 MB

    wino_wtrans<<<dim3(256),    dim3(128), 0, stream>>>(w, Up);
    wino_fused <<<dim3(2, 496), dim3(512), 0, stream>>>(x, Up, bias, out);
}